// Round 9
// baseline (17758.081 us; speedup 1.0000x reference)
//
#include <hip/hip_runtime.h>

// BiRNN: B=128, S=512, E=512, H=1024, V=50000, C=2
// Persistent cooperative kernel, 256 blocks (1/CU). NO split-K:
// block = (dir, half, 16-col chunk); owns 16 output cols x full K.
//   half=0 (h0): K = 512 (emb, fp32 gathered+split inline) + 1024 (h0 rec)
//   half=1 (h1): K = 1024 (h0) + 1024 (h1 rec)
// Weights (16 cols x K, bf16 hi/lo, frag order) LDS-resident, loaded once.
// A (h state) read via NORMAL L2-cached loads; freshness via one agent-scope
// ACQUIRE fence (buffer_inv) per phase after the barrier. h stores are sc1
// (write-through to LLC). One barrier per phase (parity double-buffer).

#define S_LEN 512

typedef short bf16x8 __attribute__((ext_vector_type(8)));
typedef float f32x4 __attribute__((ext_vector_type(4)));

__device__ __forceinline__ unsigned short f2bf(float f) {
    unsigned u = __float_as_uint(f);
    u += 0x7fff + ((u >> 16) & 1);
    return (unsigned short)(u >> 16);
}
__device__ __forceinline__ float bf2f(unsigned short h) {
    return __uint_as_float(((unsigned)h) << 16);
}
__device__ __forceinline__ f32x4 mfma16(bf16x8 a, bf16x8 b, f32x4 c) {
    return __builtin_amdgcn_mfma_f32_16x16x32_bf16(a, b, c, 0, 0, 0);
}
// relaxed agent-scope (sc1 -> LLC) stores for cross-block state
__device__ __forceinline__ void st8_cc(void* p, unsigned long long v) {
    __hip_atomic_store((unsigned long long*)p, v, __ATOMIC_RELAXED,
                       __HIP_MEMORY_SCOPE_AGENT);
}
__device__ __forceinline__ void st4_cc(void* p, float v) {
    __hip_atomic_store((int*)p, __float_as_int(v), __ATOMIC_RELAXED,
                       __HIP_MEMORY_SCOPE_AGENT);
}

// bf16x3 triple product from LDS weight (bo = ushort index of hi frag)
__device__ __forceinline__ f32x4 trip(const unsigned short* wl, int bo,
                                      bf16x8 ah, bf16x8 al, f32x4 acc) {
    bf16x8 bh = *(const bf16x8*)(wl + bo);
    bf16x8 bl = *(const bf16x8*)(wl + 32768 + bo);
    acc = mfma16(ah, bh, acc);
    acc = mfma16(ah, bl, acc);
    acc = mfma16(al, bh, acc);
    return acc;
}

__device__ __forceinline__ void cvt8(const float* p, bf16x8& ah, bf16x8& al) {
    float4 v0 = *(const float4*)p;
    float4 v1 = *(const float4*)(p + 4);
    float vv[8] = {v0.x, v0.y, v0.z, v0.w, v1.x, v1.y, v1.z, v1.w};
    #pragma unroll
    for (int j = 0; j < 8; ++j) {
        unsigned short h = f2bf(vv[j]);
        ah[j] = (short)h;
        al[j] = (short)f2bf(vv[j] - bf2f(h));
    }
}

// ws layout (bytes):
//  Hhi  @ 0         : 8 slices [(hsel*2+dir)*2+par] x 131072 ushort = 2,097,152
//  Hlo  @ 2,097,152 : 2,097,152
//  Hfin @ 4,194,304 : [2 dir][128][1024] f32 = 1,048,576
//  cnt  @ 5,242,880 : 8 x 64B
//  l2c  @ 5,243,392 : 64B
//  flag @ 5,243,456 : 64B
//  fc1  @ 5,243,520 : 32,768

// two-level last-arriver barrier (monotonic counters, cumulative targets):
// 256 blocks -> 8 counters x 32; last of each counter bumps l2c; l2c's 8th
// publishes flag = ep. Relaxed spin on flag + ONE agent ACQUIRE fence
// (emits buffer_inv -> L1/L2 refetch from LLC for this phase's A reads).
__device__ __forceinline__ void gbar(int* cnt, int* l2c, int* flag,
                                     int bid, int tid, int ep) {
    __syncthreads();   // drains vmcnt -> all sc1 stores LLC-acked
    if (tid == 0) {
        int old = __hip_atomic_fetch_add(cnt + (bid & 7) * 16, 1,
                                         __ATOMIC_RELAXED, __HIP_MEMORY_SCOPE_AGENT);
        if (old == ep * 32 - 1) {
            int old2 = __hip_atomic_fetch_add(l2c, 1, __ATOMIC_RELAXED,
                                              __HIP_MEMORY_SCOPE_AGENT);
            if (old2 == ep * 8 - 1)
                __hip_atomic_store(flag, ep, __ATOMIC_RELAXED,
                                   __HIP_MEMORY_SCOPE_AGENT);
        }
        while (__hip_atomic_load(flag, __ATOMIC_RELAXED,
                                 __HIP_MEMORY_SCOPE_AGENT) < ep)
            __builtin_amdgcn_s_sleep(1);
        __builtin_amdgcn_fence(__ATOMIC_ACQUIRE, "agent");   // buffer_inv
    }
    __syncthreads();
}

__global__ __launch_bounds__(512) void rnn_persist(
    const int* __restrict__ x, const float* __restrict__ emb,
    const float* __restrict__ f0Wi, const float* __restrict__ f0Wh,
    const float* __restrict__ f1Wi, const float* __restrict__ f1Wh,
    const float* __restrict__ b0Wi, const float* __restrict__ b0Wh,
    const float* __restrict__ b1Wi, const float* __restrict__ b1Wh,
    const float* __restrict__ f0bi, const float* __restrict__ f0bh,
    const float* __restrict__ f1bi, const float* __restrict__ f1bh,
    const float* __restrict__ b0bi, const float* __restrict__ b0bh,
    const float* __restrict__ b1bi, const float* __restrict__ b1bh,
    unsigned short* __restrict__ Hhi, unsigned short* __restrict__ Hlo,
    int* __restrict__ cnt, int* __restrict__ l2c, int* __restrict__ flag,
    float* __restrict__ Hfin)
{
    __shared__ unsigned short wlds[65536];   // 128 KiB: W-hi @0, W-lo @32768
    __shared__ unsigned short stgh[2048];    // 8 waves x 16r x 16c store bounce
    __shared__ unsigned short stgl[2048];
    __shared__ int idxs[128];

    const int bid = blockIdx.x, tid = threadIdx.x;
    const int dir  = bid >> 7;
    const int rem  = bid & 127;
    const int half = rem >> 6;               // 0: h0 chain, 1: h1 chain
    const int c0   = (rem & 63) * 16;        // output column base

    const float *WAp, *WBp, *bAp, *bBp;
    if (half == 0) {
        WAp = dir ? b0Wi : f0Wi;  WBp = dir ? b0Wh : f0Wh;
        bAp = dir ? b0bi : f0bi;  bBp = dir ? b0bh : f0bh;
    } else {
        WAp = dir ? b1Wi : f1Wi;  WBp = dir ? b1Wh : f1Wh;
        bAp = dir ? b1bi : f1bi;  bBp = dir ? b1bh : f1bh;
    }
    const int KA = half ? 1024 : 512;
    const int Kt16 = (KA + 1024) * 16;

    // ---- one-time: 16-col weight stripe -> LDS (hi/lo, frag order) ----
    for (int q = tid; q < Kt16; q += 512) {
        int k = q >> 4, c = q & 15;
        float w = (k < KA) ? WAp[(size_t)k * 1024 + c0 + c]
                           : WBp[(size_t)(k - KA) * 1024 + c0 + c];
        unsigned short h = f2bf(w);
        int o = ((k >> 3) * 16 + c) * 8 + (k & 7);
        wlds[o] = h;
        wlds[32768 + o] = f2bf(w - bf2f(h));
    }
    __syncthreads();

    const int lane = tid & 63, wid = tid >> 6;
    const int lrow = lane & 15, kgrp = lane >> 4;
    const int arow = wid * 16 + lrow;                 // A row for this lane
    const float bs = bAp[c0 + lrow] + bBp[c0 + lrow]; // bias (col-indexed)

    int ep = 0;
    for (int p = 0; p <= S_LEN; ++p) {
        const bool act = half ? (p > 0) : (p < S_LEN);
        if (act) {
            const int rp = (p + 1) & 1, wp = p & 1;
            f32x4 acc = {0.f, 0.f, 0.f, 0.f};

            if (half == 0) {
                // E part: gather fp32 emb rows, split inline (16 k-steps)
                if (tid < 128) idxs[tid] = x[tid * S_LEN + (dir ? S_LEN - 1 - p : p)];
                __syncthreads();
                const float* erow = emb + (size_t)idxs[arow] * 512;
                #pragma unroll 4
                for (int s = 0; s < 16; ++s) {
                    int kk = s * 32 + kgrp * 8;
                    bf16x8 ah, al;
                    cvt8(erow + kk, ah, al);
                    acc = trip(wlds, ((s * 4 + kgrp) * 16 + lrow) * 8, ah, al, acc);
                }
                // h0 recurrent part (32 k-steps), NORMAL L2-cached loads
                const size_t sl0 = (size_t)(dir * 2 + rp) * 131072 + (size_t)arow * 1024;
                const unsigned short* a0h = Hhi + sl0;
                const unsigned short* a0l = Hlo + sl0;
                #pragma unroll 8
                for (int s = 0; s < 32; ++s) {
                    int kk = s * 32 + kgrp * 8;
                    bf16x8 ah = *(const bf16x8*)(a0h + kk);
                    bf16x8 al = *(const bf16x8*)(a0l + kk);
                    acc = trip(wlds, ((64 + s * 4 + kgrp) * 16 + lrow) * 8, ah, al, acc);
                }
            } else {
                const size_t sl0 = (size_t)(dir * 2 + rp) * 131072 + (size_t)arow * 1024;
                const size_t sl1 = (size_t)((2 + dir) * 2 + rp) * 131072 + (size_t)arow * 1024;
                const unsigned short* a0h = Hhi + sl0;
                const unsigned short* a0l = Hlo + sl0;
                const unsigned short* a1h = Hhi + sl1;
                const unsigned short* a1l = Hlo + sl1;
                #pragma unroll 8
                for (int s = 0; s < 32; ++s) {
                    int kk = s * 32 + kgrp * 8;
                    bf16x8 ah = *(const bf16x8*)(a0h + kk);
                    bf16x8 al = *(const bf16x8*)(a0l + kk);
                    acc = trip(wlds, ((s * 4 + kgrp) * 16 + lrow) * 8, ah, al, acc);
                }
                #pragma unroll 8
                for (int s = 0; s < 32; ++s) {
                    int kk = s * 32 + kgrp * 8;
                    bf16x8 ah = *(const bf16x8*)(a1h + kk);
                    bf16x8 al = *(const bf16x8*)(a1l + kk);
                    acc = trip(wlds, ((128 + s * 4 + kgrp) * 16 + lrow) * 8, ah, al, acc);
                }
            }

            // bias + tanh + hi/lo split; transpose via per-wave LDS bounce,
            // then coalesced 8B sc1 stores.
            const size_t dsl = (size_t)((half * 2 + dir) * 2 + wp) * 131072;
            unsigned short* dh = Hhi + dsl;
            unsigned short* dl = Hlo + dsl;
            const bool fin = half && (p == S_LEN);
            #pragma unroll
            for (int r = 0; r < 4; ++r) {
                float v = tanhf(acc[r] + bs);
                unsigned short h = f2bf(v);
                int so = wid * 256 + (kgrp * 4 + r) * 16 + lrow;
                stgh[so] = h;
                stgl[so] = f2bf(v - bf2f(h));
                if (fin)
                    st4_cc(Hfin + (size_t)dir * 131072 +
                           (size_t)(wid * 16 + kgrp * 4 + r) * 1024 + c0 + lrow, v);
            }
            // within-wave ds_write -> ds_read (lgkmcnt ordered by compiler)
            {
                int rowl = lane >> 2, qo = (lane & 3) * 4;
                unsigned long long hv =
                    *(const unsigned long long*)&stgh[wid * 256 + rowl * 16 + qo];
                unsigned long long lv =
                    *(const unsigned long long*)&stgl[wid * 256 + rowl * 16 + qo];
                size_t go = (size_t)(wid * 16 + rowl) * 1024 + c0 + qo;
                st8_cc(dh + go, hv);
                st8_cc(dl + go, lv);
            }
        }
        ++ep;
        gbar(cnt, l2c, flag, bid, tid, ep);
    }
}

// ---------------------------------------------------------------------------
// Epilogue: out = (concat(h_fwd, h_bwd) @ fc1 + b1) @ fc2 + b2
// ---------------------------------------------------------------------------
__global__ __launch_bounds__(64) void fc1_kernel(
    const float* __restrict__ fc1W, const float* __restrict__ fc1b,
    const float* __restrict__ Hfin, float* __restrict__ fc1out)
{
    int r = blockIdx.x;      // 0..127
    int c = threadIdx.x;     // 0..63
    const float* hf = Hfin + (size_t)r * 1024;
    const float* hb = Hfin + 131072 + (size_t)r * 1024;
    float s = fc1b[c];
    for (int k = 0; k < 1024; ++k) s += hf[k] * fc1W[k * 64 + c];
    for (int k = 0; k < 1024; ++k) s += hb[k] * fc1W[(1024 + k) * 64 + c];
    fc1out[r * 64 + c] = s;
}

__global__ __launch_bounds__(256) void fc2_kernel(
    const float* __restrict__ fc2W, const float* __restrict__ fc2b,
    const float* __restrict__ fc1out, float* __restrict__ out)
{
    int tid = threadIdx.x;   // 128 rows x 2 cols
    int r = tid >> 1, c = tid & 1;
    const float* f = fc1out + r * 64;
    float s = fc2b[c];
    for (int k = 0; k < 64; ++k) s += f[k] * fc2W[k * 2 + c];
    out[r * 2 + c] = s;
}

extern "C" void kernel_launch(void* const* d_in, const int* in_sizes, int n_in,
                              void* d_out, int out_size, void* d_ws, size_t ws_size,
                              hipStream_t stream)
{
    const int*   x    = (const int*)d_in[0];
    const float* emb  = (const float*)d_in[1];
    const float* f0Wi = (const float*)d_in[2];
    const float* f0bi = (const float*)d_in[3];
    const float* f0Wh = (const float*)d_in[4];
    const float* f0bh = (const float*)d_in[5];
    const float* f1Wi = (const float*)d_in[6];
    const float* f1bi = (const float*)d_in[7];
    const float* f1Wh = (const float*)d_in[8];
    const float* f1bh = (const float*)d_in[9];
    const float* b0Wi = (const float*)d_in[10];
    const float* b0bi = (const float*)d_in[11];
    const float* b0Wh = (const float*)d_in[12];
    const float* b0bh = (const float*)d_in[13];
    const float* b1Wi = (const float*)d_in[14];
    const float* b1bi = (const float*)d_in[15];
    const float* b1Wh = (const float*)d_in[16];
    const float* b1bh = (const float*)d_in[17];
    const float* fc1W = (const float*)d_in[18];
    const float* fc1b = (const float*)d_in[19];
    const float* fc2W = (const float*)d_in[20];
    const float* fc2b = (const float*)d_in[21];
    float* out = (float*)d_out;

    char* wsb = (char*)d_ws;
    unsigned short* Hhi  = (unsigned short*)(wsb);
    unsigned short* Hlo  = (unsigned short*)(wsb + 2097152);
    float*          Hfin = (float*)(wsb + 4194304);
    int*            cnt  = (int*)(wsb + 5242880);
    int*            l2c  = (int*)(wsb + 5243392);
    int*            flag = (int*)(wsb + 5243456);
    float*          fc1out = (float*)(wsb + 5243520);

    // zero h state (both parities, hi+lo) and barrier counters/flag
    hipMemsetAsync(wsb, 0, 4194304, stream);
    hipMemsetAsync(wsb + 5242880, 0, 640, stream);

    void* args[] = { (void*)&x, (void*)&emb,
                     (void*)&f0Wi, (void*)&f0Wh, (void*)&f1Wi, (void*)&f1Wh,
                     (void*)&b0Wi, (void*)&b0Wh, (void*)&b1Wi, (void*)&b1Wh,
                     (void*)&f0bi, (void*)&f0bh, (void*)&f1bi, (void*)&f1bh,
                     (void*)&b0bi, (void*)&b0bh, (void*)&b1bi, (void*)&b1bh,
                     (void*)&Hhi, (void*)&Hlo, (void*)&cnt, (void*)&l2c,
                     (void*)&flag, (void*)&Hfin };
    hipLaunchCooperativeKernel((void*)rnn_persist, dim3(256), dim3(512),
                               args, 0, stream);

    fc1_kernel<<<128, 64, 0, stream>>>(fc1W, fc1b, Hfin, fc1out);
    fc2_kernel<<<1, 256, 0, stream>>>(fc2W, fc2b, fc1out, out);
}